// Round 11
// baseline (3553.135 us; speedup 1.0000x reference)
//
#include <hip/hip_runtime.h>
#include <hip/hip_bf16.h>
#include <cstdint>
#include <cstddef>

#define BTOK  8192
#define DIM   1024
#define NEXP  8
#define NHID  4096
#define HHALF 2048
#define GATE_TOK 64
#define ABASE (128 * 32)   // ushort offset of B region within one LDS buf

typedef __bf16 bf16x8 __attribute__((ext_vector_type(8)));
typedef float  floatx4 __attribute__((ext_vector_type(4)));

// ---- workspace layout (bytes) ----
#define O_COUNTS 0
#define O_BASE   256
#define O_TOKB   1024
#define O_TOKW   (O_TOKB + (size_t)NEXP*BTOK*4)
#define O_CE     (O_TOKW + (size_t)NEXP*BTOK*4)
#define O_CP     (O_CE + (size_t)2*BTOK*4)
#define O_CW     (O_CP + (size_t)2*BTOK*4)
#define O_ZBF    (O_CW + (size_t)2*BTOK*4)
#define O_W1T    (O_ZBF + (size_t)BTOK*DIM*2)
#define O_W2T    (O_W1T + (size_t)NEXP*DIM*NHID*2)
#define O_HBUF   (O_W2T + (size_t)NEXP*DIM*NHID*2)
#define WS_NEED  (O_HBUF + (size_t)2*BTOK*NHID*2)   // = 285,934,592 (proven available)

__device__ __forceinline__ void gload_lds16(const void* g, void* l) {
  __builtin_amdgcn_global_load_lds(
      (const __attribute__((address_space(1))) void*)g,
      (__attribute__((address_space(3))) void*)l, 16, 0, 0);
}

__device__ __forceinline__ ushort f2bf(float x) {
  return __builtin_bit_cast(ushort, __float2bfloat16(x));
}

// ---------------- zero counters + steal counters ----------------
__global__ void k_zcnt(int* __restrict__ counts) {
  if (threadIdx.x < 12) counts[threadIdx.x] = 0;
}

// ---------------- zero out (gemm2 accumulates atomically) ----------------
__global__ void k_zout(float* __restrict__ out) {
  int i = blockIdx.x * blockDim.x + threadIdx.x;
  float4 z4 = {0.f, 0.f, 0.f, 0.f};
  float4* o = (float4*)out;
  int n = BTOK * DIM / 4;
  for (int j = i; j < n; j += gridDim.x * blockDim.x) o[j] = z4;
}

// ---------------- transpose v2: fp32 [Z][R][C] -> bf16 [Z][C][R] ----------------
__global__ __launch_bounds__(256) void k_transpose(
    const float* __restrict__ src, __hip_bfloat16* __restrict__ dst, int R, int C) {
  __shared__ float tile[64][65];
  int zz = blockIdx.z;
  const float* s = src + (size_t)zz * R * C;
  ushort* d = (ushort*)dst + (size_t)zz * R * C;
  int c0 = blockIdx.x * 64, r0 = blockIdx.y * 64;
  int tx = threadIdx.x & 63, ty = threadIdx.x >> 6;   // 64 x 4
#pragma unroll
  for (int i = ty; i < 64; i += 4)
    tile[i][tx] = s[(size_t)(r0 + i) * C + c0 + tx];
  __syncthreads();
  int txq = threadIdx.x & 15, iy = threadIdx.x >> 4;  // 16 x 16
#pragma unroll
  for (int i = iy; i < 64; i += 16) {
    ushort4 u;
    u.x = f2bf(tile[4 * txq + 0][i]);
    u.y = f2bf(tile[4 * txq + 1][i]);
    u.z = f2bf(tile[4 * txq + 2][i]);
    u.w = f2bf(tile[4 * txq + 3][i]);
    *(ushort4*)&d[(size_t)(c0 + i) * R + r0 + 4 * txq] = u;
  }
}

// ---------------- gating ----------------
__global__ __launch_bounds__(256) void k_gate(
    const float* __restrict__ z, const float* __restrict__ Wg,
    const float* __restrict__ bg, int* __restrict__ counts,
    int* __restrict__ tokb, float* __restrict__ tokw,
    __hip_bfloat16* __restrict__ zbf) {
  __shared__ float wgT[NEXP * DIM];       // [e][d]
  __shared__ int   le[2 * GATE_TOK];
  __shared__ float lw[2 * GATE_TOK];
  __shared__ int   lr[2 * GATE_TOK];
  __shared__ int   lcnt[NEXP];
  __shared__ int   gbase[NEXP];

  int tid = threadIdx.x;
  if (tid < NEXP) lcnt[tid] = 0;
#pragma unroll
  for (int e = 0; e < NEXP; e++)
    for (int d = tid; d < DIM; d += 256)
      wgT[e * DIM + d] = Wg[d * NEXP + e];
  __syncthreads();

  int lane = tid & 63;
  int wv = tid >> 6;
  int b0 = blockIdx.x * GATE_TOK;

  for (int t = 0; t < 16; t++) {
    int lt = wv * 16 + t;
    int b = b0 + lt;
    const float4* zr4 = (const float4*)(z + (size_t)b * DIM);
    float4 zv[4];
#pragma unroll
    for (int i = 0; i < 4; i++) zv[i] = zr4[lane + 64 * i];
    ushort4* zb4 = (ushort4*)((ushort*)zbf + (size_t)b * DIM);
#pragma unroll
    for (int i = 0; i < 4; i++) {
      ushort4 u;
      u.x = f2bf(zv[i].x); u.y = f2bf(zv[i].y);
      u.z = f2bf(zv[i].z); u.w = f2bf(zv[i].w);
      zb4[lane + 64 * i] = u;
    }
    float acc[NEXP];
#pragma unroll
    for (int e = 0; e < NEXP; e++) acc[e] = 0.f;
#pragma unroll
    for (int e = 0; e < NEXP; e++) {
      const float4* wg4 = (const float4*)(wgT + e * DIM);
#pragma unroll
      for (int i = 0; i < 4; i++) {
        float4 w4 = wg4[lane + 64 * i];
        acc[e] += zv[i].x * w4.x + zv[i].y * w4.y + zv[i].z * w4.z + zv[i].w * w4.w;
      }
    }
#pragma unroll
    for (int off = 32; off > 0; off >>= 1) {
#pragma unroll
      for (int e = 0; e < NEXP; e++) acc[e] += __shfl_down(acc[e], off);
    }
    if (lane == 0) {
      float mx = -1e30f;
#pragma unroll
      for (int e = 0; e < NEXP; e++) { acc[e] += bg[e]; mx = fmaxf(mx, acc[e]); }
      float s = 0.f;
#pragma unroll
      for (int e = 0; e < NEXP; e++) { acc[e] = expf(acc[e] - mx); s += acc[e]; }
      float inv = 1.f / s;
      int i1 = -1, i2 = -1; float v1 = -1.f, v2 = -1.f;
#pragma unroll
      for (int e = 0; e < NEXP; e++) {   // stable: first index wins ties (lax.top_k)
        float w = acc[e] * inv;
        if (w > v1) { v2 = v1; i2 = i1; v1 = w; i1 = e; }
        else if (w > v2) { v2 = w; i2 = e; }
      }
      le[2 * lt] = i1;     lw[2 * lt] = v1;
      le[2 * lt + 1] = i2; lw[2 * lt + 1] = v2;
    }
  }
  __syncthreads();
  if (tid < 2 * GATE_TOK) lr[tid] = atomicAdd(&lcnt[le[tid]], 1);
  __syncthreads();
  if (tid < NEXP) gbase[tid] = atomicAdd(&counts[tid], lcnt[tid]);
  __syncthreads();
  if (tid < 2 * GATE_TOK) {
    int e = le[tid];
    int p = gbase[e] + lr[tid];
    int b = b0 + (tid >> 1);
    tokb[e * BTOK + p] = b;
    tokw[e * BTOK + p] = lw[tid];
  }
}

// base[0..7]=token prefix; base[8..16]=gemm1 tile prefix (mt*16, BN=256 over N=4096);
// base[17..25]=gemm2 UNIT prefix (mt*16 = 4 nt x 4 kseg, BN=256 over N=1024).
// mt = ceil(cnt/128).
__global__ void k_base(const int* __restrict__ counts, int* __restrict__ base) {
  if (threadIdx.x == 0 && blockIdx.x == 0) {
    int s = 0;
    for (int e = 0; e < NEXP; e++) { base[e] = s; s += counts[e]; }
    int a = 0, b = 0;
    base[8] = 0; base[17] = 0;
    for (int e = 0; e < NEXP; e++) {
      int mt = (counts[e] + 127) >> 7;
      a += mt * 16; b += mt * 16;
      base[9 + e] = a; base[18 + e] = b;
    }
  }
}

// =====================================================================
// r11: SAME 128x256 / 8-wave / BK=32 core, but ring-2 LDS (48 KB) ->
// 3 blocks/CU (launch_bounds(512,6): 24 waves/CU, VGPR cap 85, we're 64).
// Engine law from r4-r10 + m97: CU MFMA rate = resident_blocks x
// (MFMA per barrier-pair) / ~2800cyc, schedule-order-invariant.
// r10 = 2x128 -> 91/kcyc (19% util); m97 = 3x128 -> 137 (37%).
// This round buys the 3rd resident block (+50%) at the cost of a
// vmcnt(0) drain per phase (m97's own structure; r9 proved counted
// leads are worthless, co-resident blocks hide the drain).
// Ring-2 trace: phase t reads buf[t&1] (resident via phase t-1's
// VM0+mid-barrier), stages t+1 into buf[(t&1)^1] (its readers drained
// before phase t-1's end-barrier), VM0, mid-bar, MFMA, end-bar.
// gemm2: K split in 4 segs (units mt*16, 2112/768 -> duty 93%);
// atomicAdd into zeroed out, b2 folded at kseg==0.
// Swizzle (verified, 0 conflicts): LDS[r][c]=G[r][c^((r>>1)&3)], read
// chunk pc = quad ^ ((lrow>>1)&3).
// =====================================================================

#define STG3(nxt_, tt_) do {                                                 \
    gload_lds16(srcA  + (tt_) * 32, &lds[nxt_][(wv * 16) * 32]);             \
    gload_lds16(srcB0 + (tt_) * 32, &lds[nxt_][ABASE + (wv * 16) * 32]);     \
    gload_lds16(srcB1 + (tt_) * 32, &lds[nxt_][ABASE + (128 + wv * 16) * 32]);\
  } while (0)

#define PH2(cur_, STG_, VM_) do {                                           \
    const ushort* Ab_ = &lds[cur_][0];                                       \
    const ushort* Bb_ = &lds[cur_][ABASE];                                   \
    bf16x8 afr_[4], bfr_[4];                                                 \
    _Pragma("unroll")                                                        \
    for (int j_ = 0; j_ < 4; j_++)                                           \
      bfr_[j_] = __builtin_bit_cast(bf16x8,                                  \
          *(const uint4*)(Bb_ + boff + j_ * 512));                           \
    _Pragma("unroll")                                                        \
    for (int i_ = 0; i_ < 4; i_++)                                           \
      afr_[i_] = __builtin_bit_cast(bf16x8,                                  \
          *(const uint4*)(Ab_ + aoff + i_ * 512));                           \
    STG_;                                                                    \
    __builtin_amdgcn_sched_barrier(0);                                       \
    VM_;                                                                     \
    __builtin_amdgcn_s_barrier();                                            \
    __builtin_amdgcn_sched_barrier(0);                                       \
    __builtin_amdgcn_s_setprio(1);                                           \
    _Pragma("unroll")                                                        \
    for (int i_ = 0; i_ < 4; i_++)                                           \
      _Pragma("unroll")                                                      \
      for (int j_ = 0; j_ < 4; j_++)                                         \
        acc[i_][j_] = __builtin_amdgcn_mfma_f32_16x16x32_bf16(               \
            afr_[i_], bfr_[j_], acc[i_][j_], 0, 0, 0);                       \
    __builtin_amdgcn_s_setprio(0);                                           \
    __builtin_amdgcn_sched_barrier(0);                                       \
    __builtin_amdgcn_s_barrier();                                            \
  } while (0)

#define VM0  asm volatile("s_waitcnt vmcnt(0)" ::: "memory")
#define NOP_ (void)0

// ---------------- GEMM1: h = relu(zbf[tok]·W1T + b1), full N=4096 ----------------
__global__ __launch_bounds__(512, 6) void k_gemm1(
    const __hip_bfloat16* __restrict__ zbf, const __hip_bfloat16* __restrict__ w1t,
    const float* __restrict__ b1, const int* __restrict__ counts,
    const int* __restrict__ base, const int* __restrict__ tokb,
    __hip_bfloat16* __restrict__ hbuf,
    const int* __restrict__ tp, int* __restrict__ steal) {
  __shared__ __align__(16) ushort lds[2][(128 + 256) * 32];   // 48 KB
  __shared__ int sh_g;

  int tid = threadIdx.x;
  int lane = tid & 63;
  int wv = tid >> 6;       // 0..7
  int wm = wv >> 2;        // 0..1
  int wn = wv & 3;         // 0..3
  int lrow = lane & 15;
  int quad = lane >> 4;
  int pc = quad ^ ((lrow >> 1) & 3);
  int aoff = (wm * 64 + lrow) * 32 + pc * 8;
  int boff = (wn * 64 + lrow) * 32 + pc * 8;
  int srow = wv * 16 + (lane >> 2);
  int sswz = ((lane & 3) ^ ((srow >> 1) & 3)) * 8;

  const ushort* zb = (const ushort*)zbf;
  const ushort* w1 = (const ushort*)w1t;
  const int NT = DIM / 32;  // 32
  int TT = tp[8];

  for (;;) {
    if (tid == 0) sh_g = atomicAdd(steal, 1);
    __syncthreads();
    int g = sh_g;
    if (g >= TT) break;

    int e = 0;
    while (g >= tp[e + 1]) e++;
    int local = g - tp[e];
    int mte = (tp[e + 1] - tp[e]) >> 4;   // # m-tiles
    int nt = local / mte;                 // 0..15
    int mtl = local - nt * mte;
    int m0 = mtl * 128, n0 = nt * 256;    // n0 in [0,4096)
    int cnt = counts[e], gb = base[e];

    int m = m0 + srow; if (m >= cnt) m = cnt - 1;
    const ushort* srcA = zb + (size_t)tokb[e * BTOK + m] * DIM + sswz;
    const ushort* srcB0 = w1 + (size_t)(e * NHID + n0 + srow) * DIM + sswz;
    const ushort* srcB1 = w1 + (size_t)(e * NHID + n0 + 128 + srow) * DIM + sswz;

    STG3(0, 0);
    VM0;
    __builtin_amdgcn_s_barrier();

    floatx4 acc[4][4];
#pragma unroll
    for (int i = 0; i < 4; i++)
#pragma unroll
      for (int j = 0; j < 4; j++) { floatx4 zf = {0.f,0.f,0.f,0.f}; acc[i][j] = zf; }

#pragma unroll 1
    for (int t = 0; t < NT - 1; ++t) {
      PH2(t & 1, STG3((t & 1) ^ 1, t + 1), VM0);
    }
    PH2((NT - 1) & 1, NOP_, NOP_);

    float bias[4];
#pragma unroll
    for (int j = 0; j < 4; j++)
      bias[j] = b1[e * NHID + n0 + wn * 64 + j * 16 + lrow];
    ushort* hp = (ushort*)hbuf;
#pragma unroll
    for (int i = 0; i < 4; i++) {
      int mloc = wm * 64 + i * 16 + quad * 4;
#pragma unroll
      for (int r = 0; r < 4; r++) {
        int mm = m0 + mloc + r;
        if (mm < cnt) {
          ushort* hr = hp + (size_t)(gb + mm) * NHID;   // full-width rows
#pragma unroll
          for (int j = 0; j < 4; j++) {
            float v = fmaxf(acc[i][j][r] + bias[j], 0.f);
            hr[n0 + wn * 64 + j * 16 + lrow] = f2bf(v);
          }
        }
      }
    }
    __syncthreads();
  }
}

// ---------------- GEMM2: out[tok] += w*(h·W2T + b2), 4 K-seg units ----------------
__global__ __launch_bounds__(512, 6) void k_gemm2(
    const __hip_bfloat16* __restrict__ hbuf, const __hip_bfloat16* __restrict__ w2t,
    const float* __restrict__ b2, const int* __restrict__ counts,
    const int* __restrict__ base, const int* __restrict__ tokb,
    const float* __restrict__ tokw, float* __restrict__ out,
    const int* __restrict__ tp, int* __restrict__ steal) {
  __shared__ __align__(16) ushort lds[2][(128 + 256) * 32];   // 48 KB
  __shared__ int sh_g;

  int tid = threadIdx.x;
  int lane = tid & 63;
  int wv = tid >> 6;
  int wm = wv >> 2;
  int wn = wv & 3;
  int lrow = lane & 15;
  int quad = lane >> 4;
  int pc = quad ^ ((lrow >> 1) & 3);
  int aoff = (wm * 64 + lrow) * 32 + pc * 8;
  int boff = (wn * 64 + lrow) * 32 + pc * 8;
  int srow = wv * 16 + (lane >> 2);
  int sswz = ((lane & 3) ^ ((srow >> 1) & 3)) * 8;

  const ushort* hb = (const ushort*)hbuf;
  const ushort* w2 = (const ushort*)w2t;
  const int KSEG = NHID / 4;   // 1024
  const int NT = KSEG / 32;    // 32 phases per K-segment
  int TT = tp[8];              // total units (mt*16 per expert)

  for (;;) {
    if (tid == 0) sh_g = atomicAdd(steal, 1);
    __syncthreads();
    int gu = sh_g;
    if (gu >= TT) break;

    int e = 0;
    while (gu >= tp[e + 1]) e++;
    int local = gu - tp[e];
    int mtl  = local >> 4;        // mt slow
    int sub  = local & 15;
    int kseg = sub >> 2;          // 0..3
    int nt   = sub & 3;           // nt fastest (A-panel sharing)
    int m0 = mtl * 128, n0 = nt * 256;
    int cnt = counts[e], gb = base[e];

    int m = m0 + srow; if (m >= cnt) m = cnt - 1;
    const ushort* srcA = hb + (size_t)(gb + m) * NHID + kseg * KSEG + sswz;
    const ushort* srcB0 = w2 + (size_t)(e * DIM + n0 + srow) * NHID + kseg * KSEG + sswz;
    const ushort* srcB1 = w2 + (size_t)(e * DIM + n0 + 128 + srow) * NHID + kseg * KSEG + sswz;

    STG3(0, 0);
    VM0;
    __builtin_amdgcn_s_barrier();

    floatx4 acc[4][4];
#pragma unroll
    for (int i = 0; i < 4; i++)
#pragma unroll
      for (int j = 0; j < 4; j++) { floatx4 zf = {0.f,0.f,0.f,0.f}; acc[i][j] = zf; }

#pragma unroll 1
    for (int t = 0; t < NT - 1; ++t) {
      PH2(t & 1, STG3((t & 1) ^ 1, t + 1), VM0);
    }
    PH2((NT - 1) & 1, NOP_, NOP_);

#pragma unroll
    for (int i = 0; i < 4; i++) {
      int mloc = wm * 64 + i * 16 + quad * 4;
#pragma unroll
      for (int r = 0; r < 4; r++) {
        int mm = m0 + mloc + r;
        if (mm < cnt) {
          int tk  = tokb[e * BTOK + mm];
          float w = tokw[e * BTOK + mm];
#pragma unroll
          for (int j = 0; j < 4; j++) {
            int n = n0 + wn * 64 + j * 16 + lrow;
            float v = acc[i][j][r] + (kseg == 0 ? b2[e * DIM + n] : 0.f);
            atomicAdd(&out[(size_t)tk * DIM + n], w * v);
          }
        }
      }
    }
    __syncthreads();
  }
}

extern "C" void kernel_launch(void* const* d_in, const int* in_sizes, int n_in,
                              void* d_out, int out_size, void* d_ws, size_t ws_size,
                              hipStream_t stream) {
  const float* z  = (const float*)d_in[0];
  const float* Wg = (const float*)d_in[1];
  const float* bg = (const float*)d_in[2];
  const float* W1 = (const float*)d_in[3];
  const float* b1 = (const float*)d_in[4];
  const float* W2 = (const float*)d_in[5];
  const float* b2 = (const float*)d_in[6];
  float* out = (float*)d_out;
  char* ws = (char*)d_ws;
  if (ws_size < WS_NEED) return;

  int*   counts = (int*)(ws + O_COUNTS);
  int*   base   = (int*)(ws + O_BASE);
  int*   tokb   = (int*)(ws + O_TOKB);
  float* tokw   = (float*)(ws + O_TOKW);
  __hip_bfloat16* zbf  = (__hip_bfloat16*)(ws + O_ZBF);
  __hip_bfloat16* w1t  = (__hip_bfloat16*)(ws + O_W1T);
  __hip_bfloat16* w2t  = (__hip_bfloat16*)(ws + O_W2T);
  __hip_bfloat16* hbuf = (__hip_bfloat16*)(ws + O_HBUF);

  k_zcnt<<<1, 64, 0, stream>>>(counts);
  k_zout<<<512, 256, 0, stream>>>(out);
  k_transpose<<<dim3(NHID / 64, DIM / 64, NEXP), 256, 0, stream>>>(W1, w1t, DIM, NHID);
  k_transpose<<<dim3(DIM / 64, NHID / 64, NEXP), 256, 0, stream>>>(W2, w2t, NHID, DIM);
  k_gate<<<BTOK / GATE_TOK, 256, 0, stream>>>(z, Wg, bg, counts, tokb, tokw, zbf);
  k_base<<<1, 64, 0, stream>>>(counts, base);
  k_gemm1<<<768, 512, 0, stream>>>(
      zbf, w1t, b1, counts, base, tokb, hbuf, base + 8, counts + 8);
  k_gemm2<<<768, 512, 0, stream>>>(
      hbuf, w2t, b2, counts, base, tokb, tokw, out, base + 17, counts + 9);
}

// Round 12
// 873.719 us; speedup vs baseline: 4.0667x; 4.0667x over previous
//
#include <hip/hip_runtime.h>
#include <hip/hip_bf16.h>
#include <cstdint>
#include <cstddef>

#define BTOK  8192
#define DIM   1024
#define NEXP  8
#define NHID  4096
#define KSEG  1024
#define GATE_TOK 64

typedef __bf16 bf16x8 __attribute__((ext_vector_type(8)));
typedef float  floatx4 __attribute__((ext_vector_type(4)));

// ---- workspace layout (bytes) ----
#define O_COUNTS 0
#define O_BASE   256
#define O_TOKB   1024
#define O_TOKW   (O_TOKB + (size_t)NEXP*BTOK*4)
#define O_CE     (O_TOKW + (size_t)NEXP*BTOK*4)
#define O_CP     (O_CE + (size_t)2*BTOK*4)
#define O_CW     (O_CP + (size_t)2*BTOK*4)
#define O_ZBF    (O_CW + (size_t)2*BTOK*4)
#define O_W1T    (O_ZBF + (size_t)BTOK*DIM*2)
#define O_W2T    (O_W1T + (size_t)NEXP*DIM*NHID*2)
#define O_HBUF   (O_W2T + (size_t)NEXP*DIM*NHID*2)
#define WS_NEED  (O_HBUF + (size_t)2*BTOK*NHID*2)   // = 285,934,592 (proven available)

__device__ __forceinline__ void gload_lds16(const void* g, void* l) {
  __builtin_amdgcn_global_load_lds(
      (const __attribute__((address_space(1))) void*)g,
      (__attribute__((address_space(3))) void*)l, 16, 0, 0);
}

__device__ __forceinline__ ushort f2bf(float x) {
  return __builtin_bit_cast(ushort, __float2bfloat16(x));
}

// ---------------- zero counters + steal counters ----------------
__global__ void k_zcnt(int* __restrict__ counts) {
  if (threadIdx.x < 12) counts[threadIdx.x] = 0;
}

// ---------------- zero out (gemm2 accumulates atomically) ----------------
__global__ void k_zout(float* __restrict__ out) {
  int i = blockIdx.x * blockDim.x + threadIdx.x;
  float4 z4 = {0.f, 0.f, 0.f, 0.f};
  float4* o = (float4*)out;
  int n = BTOK * DIM / 4;
  for (int j = i; j < n; j += gridDim.x * blockDim.x) o[j] = z4;
}

// ---------------- transpose v2: fp32 [Z][R][C] -> bf16 [Z][C][R] ----------------
__global__ __launch_bounds__(256) void k_transpose(
    const float* __restrict__ src, __hip_bfloat16* __restrict__ dst, int R, int C) {
  __shared__ float tile[64][65];
  int zz = blockIdx.z;
  const float* s = src + (size_t)zz * R * C;
  ushort* d = (ushort*)dst + (size_t)zz * R * C;
  int c0 = blockIdx.x * 64, r0 = blockIdx.y * 64;
  int tx = threadIdx.x & 63, ty = threadIdx.x >> 6;   // 64 x 4
#pragma unroll
  for (int i = ty; i < 64; i += 4)
    tile[i][tx] = s[(size_t)(r0 + i) * C + c0 + tx];
  __syncthreads();
  int txq = threadIdx.x & 15, iy = threadIdx.x >> 4;  // 16 x 16
#pragma unroll
  for (int i = iy; i < 64; i += 16) {
    ushort4 u;
    u.x = f2bf(tile[4 * txq + 0][i]);
    u.y = f2bf(tile[4 * txq + 1][i]);
    u.z = f2bf(tile[4 * txq + 2][i]);
    u.w = f2bf(tile[4 * txq + 3][i]);
    *(ushort4*)&d[(size_t)(c0 + i) * R + r0 + 4 * txq] = u;
  }
}

// ---------------- gating ----------------
__global__ __launch_bounds__(256) void k_gate(
    const float* __restrict__ z, const float* __restrict__ Wg,
    const float* __restrict__ bg, int* __restrict__ counts,
    int* __restrict__ tokb, float* __restrict__ tokw,
    __hip_bfloat16* __restrict__ zbf) {
  __shared__ float wgT[NEXP * DIM];       // [e][d]
  __shared__ int   le[2 * GATE_TOK];
  __shared__ float lw[2 * GATE_TOK];
  __shared__ int   lr[2 * GATE_TOK];
  __shared__ int   lcnt[NEXP];
  __shared__ int   gbase[NEXP];

  int tid = threadIdx.x;
  if (tid < NEXP) lcnt[tid] = 0;
#pragma unroll
  for (int e = 0; e < NEXP; e++)
    for (int d = tid; d < DIM; d += 256)
      wgT[e * DIM + d] = Wg[d * NEXP + e];
  __syncthreads();

  int lane = tid & 63;
  int wv = tid >> 6;
  int b0 = blockIdx.x * GATE_TOK;

  for (int t = 0; t < 16; t++) {
    int lt = wv * 16 + t;
    int b = b0 + lt;
    const float4* zr4 = (const float4*)(z + (size_t)b * DIM);
    float4 zv[4];
#pragma unroll
    for (int i = 0; i < 4; i++) zv[i] = zr4[lane + 64 * i];
    ushort4* zb4 = (ushort4*)((ushort*)zbf + (size_t)b * DIM);
#pragma unroll
    for (int i = 0; i < 4; i++) {
      ushort4 u;
      u.x = f2bf(zv[i].x); u.y = f2bf(zv[i].y);
      u.z = f2bf(zv[i].z); u.w = f2bf(zv[i].w);
      zb4[lane + 64 * i] = u;
    }
    float acc[NEXP];
#pragma unroll
    for (int e = 0; e < NEXP; e++) acc[e] = 0.f;
#pragma unroll
    for (int e = 0; e < NEXP; e++) {
      const float4* wg4 = (const float4*)(wgT + e * DIM);
#pragma unroll
      for (int i = 0; i < 4; i++) {
        float4 w4 = wg4[lane + 64 * i];
        acc[e] += zv[i].x * w4.x + zv[i].y * w4.y + zv[i].z * w4.z + zv[i].w * w4.w;
      }
    }
#pragma unroll
    for (int off = 32; off > 0; off >>= 1) {
#pragma unroll
      for (int e = 0; e < NEXP; e++) acc[e] += __shfl_down(acc[e], off);
    }
    if (lane == 0) {
      float mx = -1e30f;
#pragma unroll
      for (int e = 0; e < NEXP; e++) { acc[e] += bg[e]; mx = fmaxf(mx, acc[e]); }
      float s = 0.f;
#pragma unroll
      for (int e = 0; e < NEXP; e++) { acc[e] = expf(acc[e] - mx); s += acc[e]; }
      float inv = 1.f / s;
      int i1 = -1, i2 = -1; float v1 = -1.f, v2 = -1.f;
#pragma unroll
      for (int e = 0; e < NEXP; e++) {   // stable: first index wins ties (lax.top_k)
        float w = acc[e] * inv;
        if (w > v1) { v2 = v1; i2 = i1; v1 = w; i1 = e; }
        else if (w > v2) { v2 = w; i2 = e; }
      }
      le[2 * lt] = i1;     lw[2 * lt] = v1;
      le[2 * lt + 1] = i2; lw[2 * lt + 1] = v2;
    }
  }
  __syncthreads();
  if (tid < 2 * GATE_TOK) lr[tid] = atomicAdd(&lcnt[le[tid]], 1);
  __syncthreads();
  if (tid < NEXP) gbase[tid] = atomicAdd(&counts[tid], lcnt[tid]);
  __syncthreads();
  if (tid < 2 * GATE_TOK) {
    int e = le[tid];
    int p = gbase[e] + lr[tid];
    int b = b0 + (tid >> 1);
    tokb[e * BTOK + p] = b;
    tokw[e * BTOK + p] = lw[tid];
  }
}

// base[0..7]=token prefix; base[8..16]=gemm1 unit prefix (mte*16, 16 nt over N=4096);
// base[17..25]=gemm2 unit prefix (mte*16 = 4 nt x 4 kseg).  mte = ceil(cnt/256).
__global__ void k_base(const int* __restrict__ counts, int* __restrict__ base) {
  if (threadIdx.x == 0 && blockIdx.x == 0) {
    int s = 0;
    for (int e = 0; e < NEXP; e++) { base[e] = s; s += counts[e]; }
    int a = 0, b = 0;
    base[8] = 0; base[17] = 0;
    for (int e = 0; e < NEXP; e++) {
      int mte = (counts[e] + 255) >> 8;
      a += mte * 16; b += mte * 16;
      base[9 + e] = a; base[18 + e] = b;
    }
  }
}

// =====================================================================
// r12: quadrant 8-phase 256x256 engine (m201/m248 port, re-derived).
// 8 waves (wave-tile 128x64, wm=wv>>2, wn=wv&3), BK=64, acc[8][4].
// LDS = 2 parity x 4 halves x 16KB = 128KB -> 1 block/CU, lb(512,2).
// Halves are QUADRANT row sets (staggered consumption):
//   Aq(qi): tile rows {wm*128 + qi*64 ..+64}  (slot local = wm*64+r)
//   Bq(qj): n rows    {wn*64 + qj*32 ..+32}   (slot local = wn*32+r)
// Phases per K-tile t (par=t&1): q0=(qi0,qj0) q1=(qi0,qj1) q2=(qi1,qj0)
// q3=(qi1,qj1); 16 MFMA each; afr reused across qj (A LDS-read once/qi).
// Stage 1 half/phase into parity par^1 (q3: Aq0(t+2) into par, only
// slot with no reader that phase): q0:Bq0(t+1) q1:Bq1(t+1) q2:Aq1(t+1)
// q3:Aq0(t+2).  Steady vmcnt(6) = 3 halves in flight (residency for
// phase P's top-reads ensured at P-1's vmcnt+barrier; desk-verified
// RAW/WAR for all 8 slots).  Prologue: Aq0(0),Bq0(0),Bq1(0),Aq1(0),
// Aq0(1) + VM6.  Tail: VM4/VM2/VM0.  __syncthreads between units
// drains stores (compiler emits vmcnt(0) there) so counted vmcnt never
// sees stale epilogue traffic.
// Swizzle (8-chunk rows): LDS[r][c] = G[r][c ^ ((r>>1)&7)]; read chunk
// (kk*4+quad) ^ (lrow>>1); source chunk (lane&7) ^ ((wv&1)*4 + (lane>>3)/2).
// Per-wave frag read = bijective 2KB region -> conflict-free.
// =====================================================================

#define SL(par_, idx_) (lds + ((par_) * 4 + (idx_)) * 8192)

#define STGH(dst_, P0_, P1_, tt_) do {                                       \
    gload_lds16((P0_) + (tt_) * 64, (dst_) + wv * 512);                      \
    gload_lds16((P1_) + (tt_) * 64, (dst_) + 4096 + wv * 512);               \
  } while (0)

#define VM6 asm volatile("s_waitcnt vmcnt(6)" ::: "memory")
#define VM4 asm volatile("s_waitcnt vmcnt(4)" ::: "memory")
#define VM2 asm volatile("s_waitcnt vmcnt(2)" ::: "memory")
#define VM0 asm volatile("s_waitcnt vmcnt(0)" ::: "memory")
#define NOPV (void)0
#define NOPS (void)0

#define SYNC_MID(VM_) do {                                                   \
    __builtin_amdgcn_sched_barrier(0);                                       \
    VM_;                                                                     \
    __builtin_amdgcn_s_barrier();                                            \
    __builtin_amdgcn_sched_barrier(0);                                       \
    asm volatile("s_waitcnt lgkmcnt(0)" ::: "memory");                       \
    __builtin_amdgcn_sched_barrier(0);                                       \
  } while (0)

#define MM16(qi_, qj_) do {                                                  \
    __builtin_amdgcn_s_setprio(1);                                           \
    _Pragma("unroll")                                                        \
    for (int i_ = 0; i_ < 4; i_++)                                           \
      _Pragma("unroll")                                                      \
      for (int j_ = 0; j_ < 2; j_++) {                                       \
        acc[(qi_)*4+i_][(qj_)*2+j_] = __builtin_amdgcn_mfma_f32_16x16x32_bf16(\
            afr[i_][0], bfr_[j_][0], acc[(qi_)*4+i_][(qj_)*2+j_], 0, 0, 0);  \
        acc[(qi_)*4+i_][(qj_)*2+j_] = __builtin_amdgcn_mfma_f32_16x16x32_bf16(\
            afr[i_][1], bfr_[j_][1], acc[(qi_)*4+i_][(qj_)*2+j_], 0, 0, 0);  \
      }                                                                      \
    __builtin_amdgcn_s_setprio(0);                                           \
    __builtin_amdgcn_sched_barrier(0);                                       \
    __builtin_amdgcn_s_barrier();                                            \
  } while (0)

#define PH_A(par_, qi_, qj_, STG_, VM_) do {                                 \
    const ushort* As_ = SL(par_, qi_);                                       \
    const ushort* Bs_ = SL(par_, 2 + (qj_));                                 \
    bf16x8 bfr_[2][2];                                                       \
    _Pragma("unroll")                                                        \
    for (int j_ = 0; j_ < 2; j_++) {                                         \
      bfr_[j_][0] = __builtin_bit_cast(bf16x8, *(const uint4*)(Bs_ + j_*1024 + boff0)); \
      bfr_[j_][1] = __builtin_bit_cast(bf16x8, *(const uint4*)(Bs_ + j_*1024 + boff1)); \
    }                                                                        \
    _Pragma("unroll")                                                        \
    for (int i_ = 0; i_ < 4; i_++) {                                         \
      afr[i_][0] = __builtin_bit_cast(bf16x8, *(const uint4*)(As_ + i_*1024 + aoff0)); \
      afr[i_][1] = __builtin_bit_cast(bf16x8, *(const uint4*)(As_ + i_*1024 + aoff1)); \
    }                                                                        \
    STG_;                                                                    \
    SYNC_MID(VM_);                                                           \
    MM16(qi_, qj_);                                                          \
  } while (0)

#define PH_B(par_, qi_, qj_, STG_, VM_) do {                                 \
    const ushort* Bs_ = SL(par_, 2 + (qj_));                                 \
    bf16x8 bfr_[2][2];                                                       \
    _Pragma("unroll")                                                        \
    for (int j_ = 0; j_ < 2; j_++) {                                         \
      bfr_[j_][0] = __builtin_bit_cast(bf16x8, *(const uint4*)(Bs_ + j_*1024 + boff0)); \
      bfr_[j_][1] = __builtin_bit_cast(bf16x8, *(const uint4*)(Bs_ + j_*1024 + boff1)); \
    }                                                                        \
    STG_;                                                                    \
    SYNC_MID(VM_);                                                           \
    MM16(qi_, qj_);                                                          \
  } while (0)

// shared geometry: NT=16 K-tiles of 64 per unit (K=1024)
#define GEMM_CORE(PROLOG_DONE)                                               \
    STGH(SL(0,0), pA00, pA01, 0);   /* Aq0(0) */                             \
    STGH(SL(0,2), pB00, pB01, 0);   /* Bq0(0) */                             \
    STGH(SL(0,3), pB10, pB11, 0);   /* Bq1(0) */                             \
    STGH(SL(0,1), pA10, pA11, 0);   /* Aq1(0) */                             \
    STGH(SL(1,0), pA00, pA01, 1);   /* Aq0(1) */                             \
    VM6;                                                                     \
    __builtin_amdgcn_s_barrier();                                            \
    floatx4 acc[8][4];                                                       \
    _Pragma("unroll")                                                        \
    for (int i = 0; i < 8; i++)                                              \
      _Pragma("unroll")                                                      \
      for (int j = 0; j < 4; j++) { floatx4 zf = {0.f,0.f,0.f,0.f}; acc[i][j] = zf; } \
    bf16x8 afr[4][2];                                                        \
    _Pragma("unroll 1")                                                      \
    for (int t = 0; t < 14; ++t) {                                           \
      int par = t & 1;                                                       \
      PH_A(par, 0, 0, STGH(SL(par^1,2), pB00, pB01, t+1), VM6);              \
      PH_B(par, 0, 1, STGH(SL(par^1,3), pB10, pB11, t+1), VM6);              \
      PH_A(par, 1, 0, STGH(SL(par^1,1), pA10, pA11, t+1), VM6);              \
      PH_B(par, 1, 1, STGH(SL(par,  0), pA00, pA01, t+2), VM6);              \
    }                                                                        \
    /* t = 14 (par 0): stage tile 15 halves, no Aq0(16) */                   \
    PH_A(0, 0, 0, STGH(SL(1,2), pB00, pB01, 15), VM6);                       \
    PH_B(0, 0, 1, STGH(SL(1,3), pB10, pB11, 15), VM6);                       \
    PH_A(0, 1, 0, STGH(SL(1,1), pA10, pA11, 15), VM6);                       \
    PH_B(0, 1, 1, NOPS, VM4);                                                \
    /* t = 15 (par 1): drain */                                              \
    PH_A(1, 0, 0, NOPS, VM2);                                                \
    PH_B(1, 0, 1, NOPS, VM0);                                                \
    PH_A(1, 1, 0, NOPS, NOPV);                                               \
    PH_B(1, 1, 1, NOPS, NOPV);

// ---------------- GEMM1: h = relu(zbf[tok]·W1T + b1), N=4096 ----------------
__global__ __launch_bounds__(512, 2) void k_gemm1(
    const __hip_bfloat16* __restrict__ zbf, const __hip_bfloat16* __restrict__ w1t,
    const float* __restrict__ b1, const int* __restrict__ counts,
    const int* __restrict__ base, const int* __restrict__ tokb,
    __hip_bfloat16* __restrict__ hbuf,
    const int* __restrict__ tp, int* __restrict__ steal) {
  __shared__ __align__(16) ushort lds[8 * 8192];   // 128 KB
  __shared__ int sh_g;

  int tid = threadIdx.x;
  int lane = tid & 63;
  int wv = tid >> 6;       // 0..7
  int wm = wv >> 2;        // 0..1
  int wn = wv & 3;         // 0..3
  int lrow = lane & 15;
  int quad = lane >> 4;
  int aoff0 = (wm * 64 + lrow) * 64 + ((quad ^ (lrow >> 1)) * 8);
  int aoff1 = (wm * 64 + lrow) * 64 + (((4 + quad) ^ (lrow >> 1)) * 8);
  int boff0 = (wn * 32 + lrow) * 64 + ((quad ^ (lrow >> 1)) * 8);
  int boff1 = (wn * 32 + lrow) * 64 + (((4 + quad) ^ (lrow >> 1)) * 8);
  int scsw = ((lane & 7) ^ ((wv & 1) * 4 + ((lane >> 3) >> 1))) * 8;
  int arl = wv * 8 + (lane >> 3);                // A local row within 64-run
  int brl = (wv & 3) * 8 + (lane >> 3);          // B local row within 32-run (wnPart from wv>>2/ld)

  const ushort* zb = (const ushort*)zbf;
  const ushort* w1 = (const ushort*)w1t;
  int TT = tp[8];

  for (;;) {
    if (tid == 0) sh_g = atomicAdd(steal, 1);
    __syncthreads();
    int g = sh_g;
    if (g >= TT) break;

    int e = 0;
    while (g >= tp[e + 1]) e++;
    int local = g - tp[e];
    int mte = (tp[e + 1] - tp[e]) >> 4;
    int nt = local / mte;                 // 0..15
    int mtl = local - nt * mte;
    int m0 = mtl * 256, n0 = nt * 256;
    int cnt = counts[e], gb = base[e];

    // per-lane source pointers (8): A[qi][ld], B[qj][ld]
    const ushort *pA00, *pA01, *pA10, *pA11, *pB00, *pB01, *pB10, *pB11;
    {
      int r;
      r = m0 + 0*128 + 0*64 + arl; if (r >= cnt) r = cnt - 1;
      pA00 = zb + (size_t)tokb[e * BTOK + r] * DIM + scsw;
      r = m0 + 1*128 + 0*64 + arl; if (r >= cnt) r = cnt - 1;
      pA01 = zb + (size_t)tokb[e * BTOK + r] * DIM + scsw;
      r = m0 + 0*128 + 1*64 + arl; if (r >= cnt) r = cnt - 1;
      pA10 = zb + (size_t)tokb[e * BTOK + r] * DIM + scsw;
      r = m0 + 1*128 + 1*64 + arl; if (r >= cnt) r = cnt - 1;
      pA11 = zb + (size_t)tokb[e * BTOK + r] * DIM + scsw;
      int nn;
      nn = n0 + (0*2 + (wv>>2)) * 64 + 0*32 + brl;
      pB00 = w1 + (size_t)(e * NHID + nn) * DIM + scsw;
      nn = n0 + (1*2 + (wv>>2)) * 64 + 0*32 + brl;
      pB01 = w1 + (size_t)(e * NHID + nn) * DIM + scsw;
      nn = n0 + (0*2 + (wv>>2)) * 64 + 1*32 + brl;
      pB10 = w1 + (size_t)(e * NHID + nn) * DIM + scsw;
      nn = n0 + (1*2 + (wv>>2)) * 64 + 1*32 + brl;
      pB11 = w1 + (size_t)(e * NHID + nn) * DIM + scsw;
    }

    GEMM_CORE()

    // epilogue: relu + bias, write full-width hbuf rows
    float bias[4];
#pragma unroll
    for (int j8 = 0; j8 < 4; j8++)
      bias[j8] = b1[e * NHID + n0 + wn * 64 + j8 * 16 + lrow];
    ushort* hp = (ushort*)hbuf;
#pragma unroll
    for (int i8 = 0; i8 < 8; i8++) {
      int mloc = wm * 128 + i8 * 16 + quad * 4;
#pragma unroll
      for (int r = 0; r < 4; r++) {
        int m = m0 + mloc + r;
        if (m < cnt) {
          ushort* hr = hp + (size_t)(gb + m) * NHID;
#pragma unroll
          for (int j8 = 0; j8 < 4; j8++) {
            float v = fmaxf(acc[i8][j8][r] + bias[j8], 0.f);
            hr[n0 + wn * 64 + j8 * 16 + lrow] = f2bf(v);
          }
        }
      }
    }
    __syncthreads();
  }
}

// ---------------- GEMM2: out[tok] += w*(h·W2T + b2), 4 K-segs ----------------
__global__ __launch_bounds__(512, 2) void k_gemm2(
    const __hip_bfloat16* __restrict__ hbuf, const __hip_bfloat16* __restrict__ w2t,
    const float* __restrict__ b2, const int* __restrict__ counts,
    const int* __restrict__ base, const int* __restrict__ tokb,
    const float* __restrict__ tokw, float* __restrict__ out,
    const int* __restrict__ tp, int* __restrict__ steal) {
  __shared__ __align__(16) ushort lds[8 * 8192];   // 128 KB
  __shared__ int sh_g;

  int tid = threadIdx.x;
  int lane = tid & 63;
  int wv = tid >> 6;
  int wm = wv >> 2;
  int wn = wv & 3;
  int lrow = lane & 15;
  int quad = lane >> 4;
  int aoff0 = (wm * 64 + lrow) * 64 + ((quad ^ (lrow >> 1)) * 8);
  int aoff1 = (wm * 64 + lrow) * 64 + (((4 + quad) ^ (lrow >> 1)) * 8);
  int boff0 = (wn * 32 + lrow) * 64 + ((quad ^ (lrow >> 1)) * 8);
  int boff1 = (wn * 32 + lrow) * 64 + (((4 + quad) ^ (lrow >> 1)) * 8);
  int scsw = ((lane & 7) ^ ((wv & 1) * 4 + ((lane >> 3) >> 1))) * 8;
  int arl = wv * 8 + (lane >> 3);
  int brl = (wv & 3) * 8 + (lane >> 3);

  const ushort* hb = (const ushort*)hbuf;
  const ushort* w2 = (const ushort*)w2t;
  int TT = tp[8];

  for (;;) {
    if (tid == 0) sh_g = atomicAdd(steal, 1);
    __syncthreads();
    int g = sh_g;
    if (g >= TT) break;

    int e = 0;
    while (g >= tp[e + 1]) e++;
    int local = g - tp[e];
    int mte = (tp[e + 1] - tp[e]) >> 4;
    int sub = local / mte;                // 0..15
    int mtl = local - sub * mte;
    int kseg = sub >> 2;                  // 0..3
    int nt = sub & 3;                     // 0..3
    int m0 = mtl * 256, n0 = nt * 256;
    int cnt = counts[e], gb = base[e];

    const ushort *pA00, *pA01, *pA10, *pA11, *pB00, *pB01, *pB10, *pB11;
    {
      int r;
      r = m0 + 0*128 + 0*64 + arl; if (r >= cnt) r = cnt - 1;
      pA00 = hb + (size_t)(gb + r) * NHID + kseg * KSEG + scsw;
      r = m0 + 1*128 + 0*64 + arl; if (r >= cnt) r = cnt - 1;
      pA01 = hb + (size_t)(gb + r) * NHID + kseg * KSEG + scsw;
      r = m0 + 0*128 + 1*64 + arl; if (r >= cnt) r = cnt - 1;
      pA10 = hb + (size_t)(gb + r) * NHID + kseg * KSEG + scsw;
      r = m0 + 1*128 + 1*64 + arl; if (r >= cnt) r = cnt - 1;
      pA11 = hb + (size_t)(gb + r) * NHID + kseg * KSEG + scsw;
      int nn;
      nn = n0 + (0*2 + (wv>>2)) * 64 + 0*32 + brl;
      pB00 = w2 + (size_t)(e * DIM + nn) * NHID + kseg * KSEG + scsw;
      nn = n0 + (1*2 + (wv>>2)) * 64 + 0*32 + brl;
      pB01 = w2 + (size_t)(e * DIM + nn) * NHID + kseg * KSEG + scsw;
      nn = n0 + (0*2 + (wv>>2)) * 64 + 1*32 + brl;
      pB10 = w2 + (size_t)(e * DIM + nn) * NHID + kseg * KSEG + scsw;
      nn = n0 + (1*2 + (wv>>2)) * 64 + 1*32 + brl;
      pB11 = w2 + (size_t)(e * DIM + nn) * NHID + kseg * KSEG + scsw;
    }

    GEMM_CORE()

    // epilogue: atomic accumulate into out; b2 folded by kseg==0
    float bias[4];
#pragma unroll
    for (int j8 = 0; j8 < 4; j8++)
      bias[j8] = (kseg == 0) ? b2[e * DIM + n0 + wn * 64 + j8 * 16 + lrow] : 0.f;
#pragma unroll
    for (int i8 = 0; i8 < 8; i8++) {
      int mloc = wm * 128 + i8 * 16 + quad * 4;
#pragma unroll
      for (int r = 0; r < 4; r++) {
        int m = m0 + mloc + r;
        if (m < cnt) {
          int tk  = tokb[e * BTOK + m];
          float w = tokw[e * BTOK + m];
          float* orow = out + (size_t)tk * DIM;
#pragma unroll
          for (int j8 = 0; j8 < 4; j8++) {
            int n = n0 + wn * 64 + j8 * 16 + lrow;
            atomicAdd(orow + n, w * (acc[i8][j8][r] + bias[j8]));
          }
        }
      }
    }
    __syncthreads();
  }
}

extern "C" void kernel_launch(void* const* d_in, const int* in_sizes, int n_in,
                              void* d_out, int out_size, void* d_ws, size_t ws_size,
                              hipStream_t stream) {
  const float* z  = (const float*)d_in[0];
  const float* Wg = (const float*)d_in[1];
  const float* bg = (const float*)d_in[2];
  const float* W1 = (const float*)d_in[3];
  const float* b1 = (const float*)d_in[4];
  const float* W2 = (const float*)d_in[5];
  const float* b2 = (const float*)d_in[6];
  float* out = (float*)d_out;
  char* ws = (char*)d_ws;
  if (ws_size < WS_NEED) return;

  int*   counts = (int*)(ws + O_COUNTS);
  int*   base   = (int*)(ws + O_BASE);
  int*   tokb   = (int*)(ws + O_TOKB);
  float* tokw   = (float*)(ws + O_TOKW);
  __hip_bfloat16* zbf  = (__hip_bfloat16*)(ws + O_ZBF);
  __hip_bfloat16* w1t  = (__hip_bfloat16*)(ws + O_W1T);
  __hip_bfloat16* w2t  = (__hip_bfloat16*)(ws + O_W2T);
  __hip_bfloat16* hbuf = (__hip_bfloat16*)(ws + O_HBUF);

  k_zcnt<<<1, 64, 0, stream>>>(counts);
  k_zout<<<512, 256, 0, stream>>>(out);
  k_transpose<<<dim3(NHID / 64, DIM / 64, NEXP), 256, 0, stream>>>(W1, w1t, DIM, NHID);
  k_transpose<<<dim3(DIM / 64, NHID / 64, NEXP), 256, 0, stream>>>(W2, w2t, NHID, DIM);
  k_gate<<<BTOK / GATE_TOK, 256, 0, stream>>>(z, Wg, bg, counts, tokb, tokw, zbf);
  k_base<<<1, 64, 0, stream>>>(counts, base);
  k_gemm1<<<256, 512, 0, stream>>>(
      zbf, w1t, b1, counts, base, tokb, hbuf, base + 8, counts + 8);
  k_gemm2<<<256, 512, 0, stream>>>(
      hbuf, w2t, b2, counts, base, tokb, tokw, out, base + 17, counts + 9);
}